// Round 16
// baseline (462.279 us; speedup 1.0000x reference)
//
#include <hip/hip_runtime.h>
#include <stdint.h>

#define NPTS 4096
#define BATCH 8
#define KNN 16

typedef __attribute__((ext_vector_type(8))) short short8;
typedef __attribute__((ext_vector_type(4))) float f32x4;
typedef unsigned long long u64;

// ---------------- fused 1x1 conv + LayerNorm(point) + affine + ReLU ----------
// Block = (batch, group of G output channels). Conv phase: stream X[b] from
// L2 in 4 point-chunks, accumulate G channel rows into LDS (same ci-ascending
// fmaf order per output as the old conv_kernel -> bit-identical conv values).
// LN phase: per channel, the EXACT ln_relu_kernel pass structure on the LDS
// row -> bit-identical LN output. Saves the X1/X2 HBM round-trip + a launch.
template<int CIN, int G>
__global__ __launch_bounds__(256) void conv_ln_kernel(
    const float* __restrict__ X, const float* __restrict__ W,
    const float* __restrict__ bias, const float* __restrict__ g,
    const float* __restrict__ be, float* __restrict__ Y, int cout) {
    __shared__ float rows[G * NPTS];
    __shared__ double sh[256], sh2[256];
    int b = blockIdx.x;
    int co0 = blockIdx.y * G;
    int t = threadIdx.x;
    const float* xb = X + (size_t)b * CIN * NPTS;

    // ---- conv phase ----
#pragma unroll 1
    for (int chunk = 0; chunk < 4; ++chunk) {
        int n = chunk * 1024 + t * 4;
        f32x4 acc[G];
#pragma unroll
        for (int j = 0; j < G; ++j) {
            float bj = bias[co0 + j];
            acc[j] = (f32x4){bj, bj, bj, bj};
        }
        for (int ci = 0; ci < CIN; ++ci) {
            f32x4 xv = *(const f32x4*)(xb + (size_t)ci * NPTS + n);
#pragma unroll
            for (int j = 0; j < G; ++j) {
                float w = W[(co0 + j) * CIN + ci];
                acc[j].x = fmaf(w, xv.x, acc[j].x);
                acc[j].y = fmaf(w, xv.y, acc[j].y);
                acc[j].z = fmaf(w, xv.z, acc[j].z);
                acc[j].w = fmaf(w, xv.w, acc[j].w);
            }
        }
#pragma unroll
        for (int j = 0; j < G; ++j)
            *(f32x4*)(rows + j * NPTS + n) = acc[j];
    }
    __syncthreads();

    // ---- LN phase (per channel; identical order to ln_relu_kernel) ----
#pragma unroll 1
    for (int j = 0; j < G; ++j) {
        float* row = rows + j * NPTS;
        double s = 0.0, s2 = 0.0;
        for (int i = t * 4; i < NPTS; i += 1024) {
            f32x4 v = *(const f32x4*)(row + i);
            s += (double)v.x + (double)v.y + (double)v.z + (double)v.w;
            s2 += (double)v.x * v.x + (double)v.y * v.y
                + (double)v.z * v.z + (double)v.w * v.w;
        }
        sh[t] = s; sh2[t] = s2;
        __syncthreads();
        for (int off = 128; off > 0; off >>= 1) {
            if (t < off) { sh[t] += sh[t + off]; sh2[t] += sh2[t + off]; }
            __syncthreads();
        }
        double mu = sh[0] / (double)NPTS;
        double var = sh2[0] / (double)NPTS - mu * mu;
        float rstd = (float)(1.0 / sqrt(var + 1e-5));
        float muf = (float)mu;
        float* yrow = Y + ((size_t)b * cout + co0 + j) * NPTS;
        for (int i = t * 4; i < NPTS; i += 1024) {
            f32x4 v = *(const f32x4*)(row + i);
            f32x4 gg = *(const f32x4*)(g + i);
            f32x4 bb = *(const f32x4*)(be + i);
            f32x4 o;
            o.x = fmaxf((v.x - muf) * rstd * gg.x + bb.x, 0.f);
            o.y = fmaxf((v.y - muf) * rstd * gg.y + bb.y, 0.f);
            o.z = fmaxf((v.z - muf) * rstd * gg.z + bb.z, 0.f);
            o.w = fmaxf((v.w - muf) * rstd * gg.w + bb.w, 0.f);
            *(f32x4*)(yrow + i) = o;
        }
        __syncthreads();   // sh/sh2 reused by next channel
    }
}

// ---------------- bf16 conversion + squared norms + (optional) transpose -----
// X2: [B][256][NPTS] fp32 -> Fc: [B][4][NPTS][72] bf16 (hi only),
// SQ[b][n] = sum_c x^2 (exact fp32). Chunk cc: c = cc*64..+63.
// If Xt != null: also emits Xt[b][n][256] from the SAME LDS tiles (write
// block verbatim from transpose_kernel -> identical values) and the
// standalone transpose launch (33.6 MB X2 re-read) is skipped.
#define ROW_E 72
#define ROW_B 144

__device__ inline unsigned short f2bf_rne(float x) {
    union { float f; unsigned u; } v; v.f = x;
    unsigned u = v.u;
    return (unsigned short)((u + 0x7FFFu + ((u >> 16) & 1u)) >> 16);
}

__global__ __launch_bounds__(256) void convert_kernel(
    const float* __restrict__ X2, unsigned short* __restrict__ Fc,
    float* __restrict__ SQ, float* __restrict__ Xt) {
    __shared__ float T[64][65];
    __shared__ float Q[64][4];
    int b = blockIdx.y;
    int n0 = blockIdx.x * 64;
    int t = threadIdx.x;
    int n_loc = t >> 2, cq = t & 3;
    int wave = t >> 6, lane = t & 63;
    float sacc = 0.f;
    for (int cc = 0; cc < 4; ++cc) {
        for (int r = 0; r < 16; ++r) {
            int cl = r * 4 + (t >> 6);
            T[cl][t & 63] = X2[((size_t)b * 256 + cc * 64 + cl) * NPTS + n0 + (t & 63)];
        }
        __syncthreads();
        if (Xt) {
#pragma unroll
            for (int r = 0; r < 16; ++r) {
                int n_l = wave * 16 + r;
                Xt[((size_t)b * NPTS + n0 + n_l) * 256 + cc * 64 + lane] = T[lane][n_l];
            }
        }
        size_t base = (((size_t)(b * 4 + cc) * NPTS) + n0 + n_loc) * ROW_E;
#pragma unroll
        for (int j = 0; j < 16; ++j) {
            int c = cq * 16 + j;
            float x = T[c][n_loc];
            sacc = fmaf(x, x, sacc);
            Fc[base + c] = f2bf_rne(x);
        }
        __syncthreads();
    }
    Q[n_loc][cq] = sacc;
    __syncthreads();
    if (t < 64)
        SQ[(size_t)b * NPTS + n0 + t] = Q[t][0] + Q[t][1] + Q[t][2] + Q[t][3];
}

// ---------------- fused MFMA kNN (2-way key split, packed u32 lists) ---------
// Round-15 structure + OWNER-THREAD INSERTS: scan stays fully parallel (all
// 256 threads build 32-key masks), masks are published via LDS, and the 128
// owner threads (waves 0-1, wave-uniform) drain own+partner masks into ONE
// exact top-16 list per (query, block) -> 2 lists/query globally (was 4),
// cutting cold-start+harmonic insert volume ~43%. Threshold is the exact
// running 16th (tighter than the old cross-list min). No in-block merge:
// each block writes its sorted list straight to Dp[...*2 + ks].
// u32 selection datapath: pk = (flip(d) & 0xFFFFF000) | idx12; scan
// threshold expanded to the truncation-class max (never misses a winner).
#define A_BYTES 18432                // A-half of one stage buffer
#define BUF_B   36864                // one A|B stage buffer (A 18432 + B 18432)
#define SENT32 0xFFFFFFFFu           // sorts last; never selected

__device__ inline void async_cp16(const void* g, void* l) {
    __builtin_amdgcn_global_load_lds((const __attribute__((address_space(1))) void*)g,
                                     (__attribute__((address_space(3))) void*)l, 16, 0, 0);
}

// monotone float<->uint mapping valid for negatives
__device__ inline unsigned flip_f(float d) {
    union { float f; unsigned u; } v; v.f = d;
    return v.u ^ (((unsigned)((int)v.u >> 31)) | 0x80000000u);
}
__device__ inline float unflip_f(unsigned y) {
    unsigned m = (~((unsigned)((int)y >> 31))) | 0x80000000u;
    union { unsigned u; float f; } v; v.u = y ^ m;
    return v.f;
}
// conservative float threshold for a packed u32: max float of its
// truncation class (saturated to +inf for the sentinel/NaN range)
__device__ inline float thr_of(unsigned p) {
    unsigned tb = p | 0xFFFu;
    if (tb >= 0xFF800000u) tb = 0xFF800000u;   // flip(+inf)
    return unflip_f(tb);
}

__global__ __launch_bounds__(256) void knn_mfma_kernel(
    const unsigned short* __restrict__ Fc, const float* __restrict__ SQ,
    unsigned* __restrict__ Dp) {
    __shared__ __align__(16) char smem[2 * BUF_B];     // stage dbuf; Gd aliases buf1
    __shared__ float sq_ks[128];                       // key self-norms of this k-tile
    __shared__ float thrx[128];                        // per-query exact 16th (float)
    __shared__ unsigned msk[256];                      // per-thread scan masks
    int b = blockIdx.x;
    int q0 = blockIdx.y * 128;
    int ks = blockIdx.z;                               // 0..1: 2048-key half
    int t = threadIdx.x;
    int lane = t & 63;
    int wv = t >> 6;
    int wq = wv & 1, wk = wv >> 1;
    int quad = lane >> 4;
    int l15 = lane & 15;
    const float* sqb = SQ + (size_t)b * NPTS;
    const char* FcB = (const char*)Fc + (size_t)b * 4 * NPTS * ROW_B;

    if (t < 128) thrx[t] = __int_as_float(0x7F800000);   // +inf; ordered by first barriers

    unsigned lst[KNN];
#pragma unroll
    for (int j = 0; j < KNN; ++j) lst[j] = SENT32;

    int q = t & 127, sub = t >> 7;

    // ---- prologue: stage tile g=0 (kt=0, kc=0) into buf0 ----
    {
        const char* gA = FcB + (size_t)q0 * ROW_B;               // kc=0, A panel
        const char* gB = FcB + (size_t)(ks * 2048) * ROW_B;      // kc=0, kbase
#pragma unroll
        for (int i = 0; i < 9; ++i) {
            int chunk = (i * 4 + wv) * 1024;
            const char* g = (chunk < A_BYTES) ? (gA + chunk) : (gB + (chunk - A_BYTES));
            async_cp16(g + lane * 16, smem + chunk);
        }
    }
    __syncthreads();   // prologue staging drained

    for (int kt = 0; kt < 16; ++kt) {
        int kbase = ks * 2048 + kt * 128;
        if (t < 128) sq_ks[t] = sqb[kbase + t];   // prev dump readers done (post-scan bar)
        f32x4 acc[4][4];
#pragma unroll
        for (int i = 0; i < 4; ++i)
#pragma unroll
            for (int j = 0; j < 4; ++j) acc[i][j] = (f32x4){0.f, 0.f, 0.f, 0.f};

#pragma unroll 1
        for (int kc = 0; kc < 4; ++kc) {
            int g = kt * 4 + kc;
            int gn = g + 1;
            if (gn < 64) {     // prefetch tile g+1 into the other buffer
                int kcn = gn & 3, ktn = gn >> 2;
                const char* gA = FcB + ((size_t)kcn * NPTS + q0) * ROW_B;
                const char* gB = FcB + ((size_t)kcn * NPTS + ks * 2048 + ktn * 128) * ROW_B;
                char* dst = smem + (gn & 1) * BUF_B;
#pragma unroll
                for (int i = 0; i < 9; ++i) {
                    int chunk = (i * 4 + wv) * 1024;
                    const char* gp = (chunk < A_BYTES) ? (gA + chunk) : (gB + (chunk - A_BYTES));
                    async_cp16(gp + lane * 16, dst + chunk);
                }
            }
            const char* base = smem + (g & 1) * BUF_B;
#pragma unroll
            for (int kss = 0; kss < 2; ++kss) {
                int coff = kss * 64 + quad * 16;
                short8 a[4], bf[4];
#pragma unroll
                for (int tq = 0; tq < 4; ++tq)
                    a[tq] = *(const short8*)(base + (wq * 64 + tq * 16 + l15) * ROW_B + coff);
#pragma unroll
                for (int tk = 0; tk < 4; ++tk)
                    bf[tk] = *(const short8*)(base + A_BYTES + (wk * 64 + tk * 16 + l15) * ROW_B + coff);
#pragma unroll
                for (int tq = 0; tq < 4; ++tq)
#pragma unroll
                    for (int tk = 0; tk < 4; ++tk)
                        acc[tq][tk] = __builtin_amdgcn_mfma_f32_16x16x32_bf16(
                            a[tq], bf[tk], acc[tq][tk], 0, 0, 0);
            }
            __syncthreads();   // prefetch(g+1) drained; all reads of buf[g&1] done
        }

        // selection: two 64-key phases, Gd (34816 B) aliases buf1 (36864 B);
        // buf1's last compute reads finished at the kc=3 barrier above.
        float* Gd = (float*)(smem + BUF_B);
        const float* gq = Gd + (size_t)q * 68 + sub * 32;   // scan segment
#pragma unroll 1
        for (int h = 0; h < 2; ++h) {
            if (wk == h) {
                // dump d' = sq_k - 2*G, transposed scatter (b32, 2-way banks)
#pragma unroll
                for (int tk = 0; tk < 4; ++tk) {
                    float sqk = sq_ks[h * 64 + tk * 16 + l15];
#pragma unroll
                    for (int tq = 0; tq < 4; ++tq) {
                        float* gp = Gd + (size_t)(wq * 64 + tq * 16 + quad * 4) * 68
                                  + tk * 16 + l15;
                        f32x4 g = acc[tq][tk];
                        gp[0]   = fmaf(-2.f, g.x, sqk);
                        gp[68]  = fmaf(-2.f, g.y, sqk);
                        gp[136] = fmaf(-2.f, g.z, sqk);
                        gp[204] = fmaf(-2.f, g.w, sqk);
                    }
                }
            }
            __syncthreads();   // dump visible to scanners
            // threshold: exact running 16th of the query's single list
            // (owners have it in-register; scanners read last published copy
            //  -- conservative: thresholds only tighten over time)
            float thrf = (t < 128) ? thr_of(lst[KNN - 1]) : thrx[q];
            // phase 1: vectorized 32-key scan -> candidate mask (bit j)
            unsigned mask = 0;
#pragma unroll
            for (int i = 7; i >= 0; --i) {
                f32x4 v = *(const f32x4*)(gq + i * 4);
                mask = mask + mask + (unsigned)(v.w <= thrf);
                mask = mask + mask + (unsigned)(v.z <= thrf);
                mask = mask + mask + (unsigned)(v.y <= thrf);
                mask = mask + mask + (unsigned)(v.x <= thrf);
            }
            msk[t] = mask;
            __syncthreads();   // masks published
            // phase 2: owner threads (waves 0-1) drain own + partner masks
            if (t < 128) {
                unsigned m0 = mask;                 // keys h*64 + 0..31
                unsigned m1 = msk[t + 128];         // keys h*64 + 32..63
                const float* gq0 = Gd + (size_t)t * 68;
                while (__any((int)((m0 | m1) != 0u))) {
                    if (m0 | m1) {
                        int col;
                        if (m0) { int j = __ffs(m0) - 1; m0 &= m0 - 1u; col = j; }
                        else    { int j = __ffs(m1) - 1; m1 &= m1 - 1u; col = 32 + j; }
                        float d = gq0[col];
                        unsigned pk = (flip_f(d) & 0xFFFFF000u)
                                    | (unsigned)(kbase + h * 64 + col);
                        if (pk < lst[KNN - 1]) {
                            lst[KNN - 1] = pk;
#pragma unroll
                            for (int s = KNN - 1; s > 0; --s) {
                                if (lst[s] < lst[s - 1]) {
                                    unsigned tmp = lst[s]; lst[s] = lst[s - 1]; lst[s - 1] = tmp;
                                }
                            }
                        }
                    }
                }
                thrx[t] = thr_of(lst[KNN - 1]);     // publish fresh exact 16th
            }
            __syncthreads();   // inserts done: h1 dump / next-kt staging safe
        }
    }

    // ---- write the exact per-(query, block) sorted 16-list ----
    if (t < 128) {
        unsigned* outp = Dp + ((size_t)((b * NPTS + q0 + t) * 2 + ks)) * KNN;
#pragma unroll
        for (int k = 0; k < KNN; ++k) outp[k] = lst[k];
    }
}

// ---------------- transpose: X2 [b][c][n] -> Xt [b][n][256] ------------------
// Fallback only (ws too small for a dedicated Xt region).
__global__ __launch_bounds__(256) void transpose_kernel(
    const float* __restrict__ X2, float* __restrict__ Xt) {
    __shared__ float T[64][65];
    int b = blockIdx.x;
    int n0 = blockIdx.y * 64;
    int t = threadIdx.x;
    int wave = t >> 6, lane = t & 63;
    for (int cc = 0; cc < 4; ++cc) {
        for (int r = 0; r < 16; ++r) {
            int cl = r * 4 + (t >> 6);
            T[cl][t & 63] = X2[((size_t)b * 256 + cc * 64 + cl) * NPTS + n0 + (t & 63)];
        }
        __syncthreads();
#pragma unroll
        for (int r = 0; r < 16; ++r) {
            int n_l = wave * 16 + r;
            Xt[((size_t)b * NPTS + n0 + n_l) * 256 + cc * 64 + lane] = T[lane][n_l];
        }
        __syncthreads();
    }
}

// ---------------- fused merge2 + gather + max over K + partial pool ----------
__global__ __launch_bounds__(256) void gather_pool_kernel(
    const float* __restrict__ Xt, const unsigned* __restrict__ Dp,
    float* __restrict__ Pp) {
    __shared__ int idxs[16][KNN];
    int b = blockIdx.x, blk = blockIdx.y;
    int t = threadIdx.x;
    if (t < 16) {
        int qg = b * NPTS + blk * 16 + t;
        const unsigned* L0 = Dp + (size_t)qg * 2 * KNN;
        const unsigned* L1 = L0 + KNN;
        int p0 = 0, p1 = 0;
#pragma unroll 1
        for (int k = 0; k < KNN; ++k) {
            bool ta = (p1 >= KNN) || (p0 < KNN && L0[p0] < L1[p1]);
            idxs[t][k] = (int)((ta ? L0[p0++] : L1[p1++]) & 0xFFFu);
        }
    }
    __syncthreads();
    int wv = t >> 6, lane = t & 63;
    const float* xb = Xt + (size_t)b * NPTS * 256;
    f32x4 sum = (f32x4){0.f, 0.f, 0.f, 0.f};
#pragma unroll 1
    for (int i = 0; i < 4; ++i) {
        const int* idp = idxs[wv * 4 + i];
        f32x4 m = *(const f32x4*)(xb + (size_t)idp[0] * 256 + lane * 4);
#pragma unroll
        for (int k = 1; k < KNN; ++k) {
            f32x4 v = *(const f32x4*)(xb + (size_t)idp[k] * 256 + lane * 4);
            m.x = fmaxf(m.x, v.x); m.y = fmaxf(m.y, v.y);
            m.z = fmaxf(m.z, v.z); m.w = fmaxf(m.w, v.w);
        }
        sum.x += m.x; sum.y += m.y; sum.z += m.z; sum.w += m.w;
    }
    __shared__ float S[4][256];
    *(f32x4*)&S[wv][lane * 4] = sum;
    __syncthreads();
    Pp[((size_t)b * 256 + blk) * 256 + t] = S[0][t] + S[1][t] + S[2][t] + S[3][t];
}

// ---------------- fused final pool + MLP (grid = 8 blocks, one per batch) ----
__global__ __launch_bounds__(256) void pool_mlp_kernel(
    const float* __restrict__ Pp,
    const float* __restrict__ gw0, const float* __restrict__ gb0,
    const float* __restrict__ gw1, const float* __restrict__ gb1,
    const float* __restrict__ gw2, const float* __restrict__ gb2,
    float* __restrict__ out) {
    __shared__ float P[256];
    __shared__ float h1[128];
    __shared__ float h2[64];
    int b = blockIdx.x, t = threadIdx.x;
    double s = 0.0;
#pragma unroll 4
    for (int j = 0; j < 256; ++j) s += (double)Pp[((size_t)b * 256 + j) * 256 + t];
    P[t] = (float)(s / (double)NPTS);
    __syncthreads();
    if (t < 128) {
        const float* w = gw0 + t * 256;
        double acc = 0.0;
        for (int c = 0; c < 256; ++c) acc += (double)P[c] * (double)w[c];
        float v = gb0[t] + (float)acc;
        h1[t] = v > 0.f ? v : 0.f;
    }
    __syncthreads();
    if (t < 64) {
        const float* w = gw1 + t * 128;
        double acc = 0.0;
        for (int c = 0; c < 128; ++c) acc += (double)h1[c] * (double)w[c];
        float v = gb1[t] + (float)acc;
        h2[t] = v > 0.f ? v : 0.f;
    }
    __syncthreads();
    if (t == 0) {
        double acc = 0.0;
        for (int c = 0; c < 64; ++c) acc += (double)h2[c] * (double)gw2[c];
        out[b] = gb2[0] + (float)acc;
    }
}

extern "C" void kernel_launch(void* const* d_in, const int* in_sizes, int n_in,
                              void* d_out, int out_size, void* d_ws, size_t ws_size,
                              hipStream_t stream) {
    const float* pc  = (const float*)d_in[0];
    const float* w0  = (const float*)d_in[1];
    const float* b0  = (const float*)d_in[2];
    const float* g0  = (const float*)d_in[3];
    const float* be0 = (const float*)d_in[4];
    const float* w1  = (const float*)d_in[5];
    const float* b1  = (const float*)d_in[6];
    const float* g1  = (const float*)d_in[7];
    const float* be1 = (const float*)d_in[8];
    const float* w2  = (const float*)d_in[9];
    const float* b2  = (const float*)d_in[10];
    const float* g2  = (const float*)d_in[11];
    const float* be2 = (const float*)d_in[12];
    const float* gw0 = (const float*)d_in[13];
    const float* gb0 = (const float*)d_in[14];
    const float* gw1 = (const float*)d_in[15];
    const float* gb1 = (const float*)d_in[16];
    const float* gw2 = (const float*)d_in[17];
    const float* gb2 = (const float*)d_in[18];
    float* out = (float*)d_out;

    // ws layout (floats). Region reuse timeline:
    //   X0 (2,097,152 f): conv0 act -> Dp (knn packed u32 lists, 1,048,576 u32
    //                     = 4 MB; live through gather_pool)
    //   X2 (8,388,608 f): conv2 act (live through convert/transpose)
    //   R  (11,534,336 f): X1 (conv1) -> Fc (4,718,592 f: bf16-hi)
    //                      [fallback only: -> Xt after knn]
    //   tail: SQ, P(pad), Pp, [roomy only: Xt2]
    float* ws = (float*)d_ws;
    float* X0 = ws;
    float* X2 = X0 + 2097152;
    float* R  = X2 + 8388608;
    float* X1 = R;
    unsigned short* Fc = (unsigned short*)R;          // 9,437,184 shorts (hi only)
    unsigned* Dp = (unsigned*)X0;                     // 1,048,576 u32 (2 lists/q)
    float* SQ = R + 11534336;                         // 32,768 f
    float* P  = SQ + 32768;                           // 2,048 f (layout pad)
    float* Pp = P + 2048;                             // 524,288 f
    float* Xt2 = Pp + 524288;                         // 8,388,608 f (roomy only)

    // roomy: dedicated Xt region -> convert emits Xt from its LDS tiles and
    // the standalone transpose launch (+33.6 MB X2 re-read) is skipped.
    bool roomy = ws_size >= (size_t)(22579200ull + 8388608ull) * 4ull;
    float* Xt = roomy ? Xt2 : R;   // fallback: Xt overwrites Fc after knn

    // fused conv+LN: grid (batch, co-groups) -> same-batch blocks co-XCD.
    conv_ln_kernel<3, 2><<<dim3(BATCH, 64 / 2), 256, 0, stream>>>(
        pc, w0, b0, g0, be0, X0, 64);
    conv_ln_kernel<64, 4><<<dim3(BATCH, 128 / 4), 256, 0, stream>>>(
        X0, w1, b1, g1, be1, X1, 128);
    conv_ln_kernel<128, 4><<<dim3(BATCH, 256 / 4), 256, 0, stream>>>(
        X1, w2, b2, g2, be2, X2, 256);

    convert_kernel<<<dim3(NPTS / 64, BATCH), 256, 0, stream>>>(
        X2, Fc, SQ, roomy ? Xt2 : nullptr);                      // overwrites X1 (dead)
    knn_mfma_kernel<<<dim3(BATCH, 32, 2), 256, 0, stream>>>(Fc, SQ, Dp);
    if (!roomy)
        transpose_kernel<<<dim3(BATCH, NPTS / 64), 256, 0, stream>>>(X2, Xt);
    gather_pool_kernel<<<dim3(BATCH, 256), 256, 0, stream>>>(Xt, Dp, Pp);
    pool_mlp_kernel<<<dim3(BATCH), 256, 0, stream>>>(Pp, gw0, gb0, gw1, gb1, gw2, gb2, out);
}

// Round 17
// 438.192 us; speedup vs baseline: 1.0550x; 1.0550x over previous
//
#include <hip/hip_runtime.h>
#include <stdint.h>

#define NPTS 4096
#define BATCH 8
#define KNN 16

typedef __attribute__((ext_vector_type(8))) short short8;
typedef __attribute__((ext_vector_type(4))) float f32x4;
typedef unsigned long long u64;

// ---------------- fused 1x1 conv + LayerNorm(point) + affine + ReLU ----------
// Block = (batch, group of G output channels). Conv phase: stream X[b] from
// L2 in 4 point-chunks, accumulate G channel rows into LDS (same ci-ascending
// fmaf order per output as the old conv_kernel -> bit-identical conv values).
// LN phase: per channel, the EXACT ln_relu_kernel pass structure on the LDS
// row -> bit-identical LN output. Saves the X1/X2 HBM round-trip + a launch.
template<int CIN, int G>
__global__ __launch_bounds__(256) void conv_ln_kernel(
    const float* __restrict__ X, const float* __restrict__ W,
    const float* __restrict__ bias, const float* __restrict__ g,
    const float* __restrict__ be, float* __restrict__ Y, int cout) {
    __shared__ float rows[G * NPTS];
    __shared__ double sh[256], sh2[256];
    int b = blockIdx.x;
    int co0 = blockIdx.y * G;
    int t = threadIdx.x;
    const float* xb = X + (size_t)b * CIN * NPTS;

    // ---- conv phase ----
#pragma unroll 1
    for (int chunk = 0; chunk < 4; ++chunk) {
        int n = chunk * 1024 + t * 4;
        f32x4 acc[G];
#pragma unroll
        for (int j = 0; j < G; ++j) {
            float bj = bias[co0 + j];
            acc[j] = (f32x4){bj, bj, bj, bj};
        }
        for (int ci = 0; ci < CIN; ++ci) {
            f32x4 xv = *(const f32x4*)(xb + (size_t)ci * NPTS + n);
#pragma unroll
            for (int j = 0; j < G; ++j) {
                float w = W[(co0 + j) * CIN + ci];
                acc[j].x = fmaf(w, xv.x, acc[j].x);
                acc[j].y = fmaf(w, xv.y, acc[j].y);
                acc[j].z = fmaf(w, xv.z, acc[j].z);
                acc[j].w = fmaf(w, xv.w, acc[j].w);
            }
        }
#pragma unroll
        for (int j = 0; j < G; ++j)
            *(f32x4*)(rows + j * NPTS + n) = acc[j];
    }
    __syncthreads();

    // ---- LN phase (per channel; identical order to ln_relu_kernel) ----
#pragma unroll 1
    for (int j = 0; j < G; ++j) {
        float* row = rows + j * NPTS;
        double s = 0.0, s2 = 0.0;
        for (int i = t * 4; i < NPTS; i += 1024) {
            f32x4 v = *(const f32x4*)(row + i);
            s += (double)v.x + (double)v.y + (double)v.z + (double)v.w;
            s2 += (double)v.x * v.x + (double)v.y * v.y
                + (double)v.z * v.z + (double)v.w * v.w;
        }
        sh[t] = s; sh2[t] = s2;
        __syncthreads();
        for (int off = 128; off > 0; off >>= 1) {
            if (t < off) { sh[t] += sh[t + off]; sh2[t] += sh2[t + off]; }
            __syncthreads();
        }
        double mu = sh[0] / (double)NPTS;
        double var = sh2[0] / (double)NPTS - mu * mu;
        float rstd = (float)(1.0 / sqrt(var + 1e-5));
        float muf = (float)mu;
        float* yrow = Y + ((size_t)b * cout + co0 + j) * NPTS;
        for (int i = t * 4; i < NPTS; i += 1024) {
            f32x4 v = *(const f32x4*)(row + i);
            f32x4 gg = *(const f32x4*)(g + i);
            f32x4 bb = *(const f32x4*)(be + i);
            f32x4 o;
            o.x = fmaxf((v.x - muf) * rstd * gg.x + bb.x, 0.f);
            o.y = fmaxf((v.y - muf) * rstd * gg.y + bb.y, 0.f);
            o.z = fmaxf((v.z - muf) * rstd * gg.z + bb.z, 0.f);
            o.w = fmaxf((v.w - muf) * rstd * gg.w + bb.w, 0.f);
            *(f32x4*)(yrow + i) = o;
        }
        __syncthreads();   // sh/sh2 reused by next channel
    }
}

// ---------------- bf16 conversion + squared norms + (optional) transpose -----
// X2: [B][256][NPTS] fp32 -> Fc: [B][4][NPTS][72] bf16 (hi only),
// SQ[b][n] = sum_c x^2 (exact fp32). Chunk cc: c = cc*64..+63.
// If Xt != null: also emits Xt[b][n][256] from the SAME LDS tiles (write
// block verbatim from transpose_kernel -> identical values) and the
// standalone transpose launch (33.6 MB X2 re-read) is skipped.
#define ROW_E 72
#define ROW_B 144

__device__ inline unsigned short f2bf_rne(float x) {
    union { float f; unsigned u; } v; v.f = x;
    unsigned u = v.u;
    return (unsigned short)((u + 0x7FFFu + ((u >> 16) & 1u)) >> 16);
}

__global__ __launch_bounds__(256) void convert_kernel(
    const float* __restrict__ X2, unsigned short* __restrict__ Fc,
    float* __restrict__ SQ, float* __restrict__ Xt) {
    __shared__ float T[64][65];
    __shared__ float Q[64][4];
    int b = blockIdx.y;
    int n0 = blockIdx.x * 64;
    int t = threadIdx.x;
    int n_loc = t >> 2, cq = t & 3;
    int wave = t >> 6, lane = t & 63;
    float sacc = 0.f;
    for (int cc = 0; cc < 4; ++cc) {
        for (int r = 0; r < 16; ++r) {
            int cl = r * 4 + (t >> 6);
            T[cl][t & 63] = X2[((size_t)b * 256 + cc * 64 + cl) * NPTS + n0 + (t & 63)];
        }
        __syncthreads();
        if (Xt) {
#pragma unroll
            for (int r = 0; r < 16; ++r) {
                int n_l = wave * 16 + r;
                Xt[((size_t)b * NPTS + n0 + n_l) * 256 + cc * 64 + lane] = T[lane][n_l];
            }
        }
        size_t base = (((size_t)(b * 4 + cc) * NPTS) + n0 + n_loc) * ROW_E;
#pragma unroll
        for (int j = 0; j < 16; ++j) {
            int c = cq * 16 + j;
            float x = T[c][n_loc];
            sacc = fmaf(x, x, sacc);
            Fc[base + c] = f2bf_rne(x);
        }
        __syncthreads();
    }
    Q[n_loc][cq] = sacc;
    __syncthreads();
    if (t < 64)
        SQ[(size_t)b * NPTS + n0 + t] = Q[t][0] + Q[t][1] + Q[t][2] + Q[t][3];
}

// ---------------- fused MFMA kNN (2-way key split, packed u32 lists) ---------
// Round-15 verified optimum (r16's owner-thread drain regressed: VALU work
// fell but wave-max serialization + extra barrier grew the critical path).
// Structure: round-12 double-buffered staging, 2-way key split (ks in {0,1},
// 2048 keys per block, kt=16), 4 lists/query drained in parallel by the two
// sub-threads of each query (different waves -> concurrent inserts).
// u32 selection datapath: pk = (flip(d) & 0xFFFFF000) | idx12; scan
// threshold expanded to the truncation-class max (never misses a winner).
#define A_BYTES 18432                // A-half of one stage buffer
#define BUF_B   36864                // one A|B stage buffer (A 18432 + B 18432)
#define SENT32 0xFFFFFFFFu           // sorts last; never selected

__device__ inline void async_cp16(const void* g, void* l) {
    __builtin_amdgcn_global_load_lds((const __attribute__((address_space(1))) void*)g,
                                     (__attribute__((address_space(3))) void*)l, 16, 0, 0);
}

// monotone float<->uint mapping valid for negatives
__device__ inline unsigned flip_f(float d) {
    union { float f; unsigned u; } v; v.f = d;
    return v.u ^ (((unsigned)((int)v.u >> 31)) | 0x80000000u);
}
__device__ inline float unflip_f(unsigned y) {
    unsigned m = (~((unsigned)((int)y >> 31))) | 0x80000000u;
    union { unsigned u; float f; } v; v.u = y ^ m;
    return v.f;
}
// conservative float threshold for a packed u32: max float of its
// truncation class (saturated to +inf for the sentinel/NaN range)
__device__ inline float thr_of(unsigned p) {
    unsigned tb = p | 0xFFFu;
    if (tb >= 0xFF800000u) tb = 0xFF800000u;   // flip(+inf)
    return unflip_f(tb);
}

__global__ __launch_bounds__(256) void knn_mfma_kernel(
    const unsigned short* __restrict__ Fc, const float* __restrict__ SQ,
    unsigned* __restrict__ Dp) {
    __shared__ __align__(16) char smem[2 * BUF_B];     // stage dbuf; Gd aliases buf1
    __shared__ float sq_ks[128];                       // key self-norms of this k-tile
    __shared__ float thrx[256];                        // per-thread 16th-best (float)
    int b = blockIdx.x;
    int q0 = blockIdx.y * 128;
    int ks = blockIdx.z;                               // 0..1: 2048-key half
    int t = threadIdx.x;
    int lane = t & 63;
    int wv = t >> 6;
    int wq = wv & 1, wk = wv >> 1;
    int quad = lane >> 4;
    int l15 = lane & 15;
    const float* sqb = SQ + (size_t)b * NPTS;
    const char* FcB = (const char*)Fc + (size_t)b * 4 * NPTS * ROW_B;

    thrx[t] = __int_as_float(0x7F800000);   // +inf; visible after first barriers

    unsigned lst[KNN];
#pragma unroll
    for (int j = 0; j < KNN; ++j) lst[j] = SENT32;

    int q = t & 127, sub = t >> 7;

    // ---- prologue: stage tile g=0 (kt=0, kc=0) into buf0 ----
    {
        const char* gA = FcB + (size_t)q0 * ROW_B;               // kc=0, A panel
        const char* gB = FcB + (size_t)(ks * 2048) * ROW_B;      // kc=0, kbase
#pragma unroll
        for (int i = 0; i < 9; ++i) {
            int chunk = (i * 4 + wv) * 1024;
            const char* g = (chunk < A_BYTES) ? (gA + chunk) : (gB + (chunk - A_BYTES));
            async_cp16(g + lane * 16, smem + chunk);
        }
    }
    __syncthreads();   // prologue staging drained

    for (int kt = 0; kt < 16; ++kt) {
        int kbase = ks * 2048 + kt * 128;
        if (t < 128) sq_ks[t] = sqb[kbase + t];   // prev dump readers done (post-scan bar)
        f32x4 acc[4][4];
#pragma unroll
        for (int i = 0; i < 4; ++i)
#pragma unroll
            for (int j = 0; j < 4; ++j) acc[i][j] = (f32x4){0.f, 0.f, 0.f, 0.f};

#pragma unroll 1
        for (int kc = 0; kc < 4; ++kc) {
            int g = kt * 4 + kc;
            int gn = g + 1;
            if (gn < 64) {     // prefetch tile g+1 into the other buffer
                int kcn = gn & 3, ktn = gn >> 2;
                const char* gA = FcB + ((size_t)kcn * NPTS + q0) * ROW_B;
                const char* gB = FcB + ((size_t)kcn * NPTS + ks * 2048 + ktn * 128) * ROW_B;
                char* dst = smem + (gn & 1) * BUF_B;
#pragma unroll
                for (int i = 0; i < 9; ++i) {
                    int chunk = (i * 4 + wv) * 1024;
                    const char* gp = (chunk < A_BYTES) ? (gA + chunk) : (gB + (chunk - A_BYTES));
                    async_cp16(gp + lane * 16, dst + chunk);
                }
            }
            const char* base = smem + (g & 1) * BUF_B;
#pragma unroll
            for (int kss = 0; kss < 2; ++kss) {
                int coff = kss * 64 + quad * 16;
                short8 a[4], bf[4];
#pragma unroll
                for (int tq = 0; tq < 4; ++tq)
                    a[tq] = *(const short8*)(base + (wq * 64 + tq * 16 + l15) * ROW_B + coff);
#pragma unroll
                for (int tk = 0; tk < 4; ++tk)
                    bf[tk] = *(const short8*)(base + A_BYTES + (wk * 64 + tk * 16 + l15) * ROW_B + coff);
#pragma unroll
                for (int tq = 0; tq < 4; ++tq)
#pragma unroll
                    for (int tk = 0; tk < 4; ++tk)
                        acc[tq][tk] = __builtin_amdgcn_mfma_f32_16x16x32_bf16(
                            a[tq], bf[tk], acc[tq][tk], 0, 0, 0);
            }
            __syncthreads();   // prefetch(g+1) drained; all reads of buf[g&1] done
        }

        // selection: two 64-key halves, Gd (34816 B) aliases buf1 (36864 B);
        // buf1's last compute reads finished at the kc=3 barrier above.
        float* Gd = (float*)(smem + BUF_B);
        const float* gq = Gd + (size_t)q * 68 + sub * 32;
#pragma unroll 1
        for (int h = 0; h < 2; ++h) {
            if (wk == h) {
                // dump d' = sq_k - 2*G, transposed scatter (b32, 2-way banks)
#pragma unroll
                for (int tk = 0; tk < 4; ++tk) {
                    float sqk = sq_ks[h * 64 + tk * 16 + l15];
#pragma unroll
                    for (int tq = 0; tq < 4; ++tq) {
                        float* gp = Gd + (size_t)(wq * 64 + tq * 16 + quad * 4) * 68
                                  + tk * 16 + l15;
                        f32x4 g = acc[tq][tk];
                        gp[0]   = fmaf(-2.f, g.x, sqk);
                        gp[68]  = fmaf(-2.f, g.y, sqk);
                        gp[136] = fmaf(-2.f, g.z, sqk);
                        gp[204] = fmaf(-2.f, g.w, sqk);
                    }
                }
            }
            __syncthreads();   // dump visible to scanners
            // fresh cross-thread threshold (conservative regardless of race)
            float thrf = fminf(thr_of(lst[KNN - 1]), thrx[t ^ 128]);
            // phase 1: vectorized row scan -> candidate mask (bit j = key j)
            unsigned mask = 0;
#pragma unroll
            for (int i = 7; i >= 0; --i) {
                f32x4 v = *(const f32x4*)(gq + i * 4);
                mask = mask + mask + (unsigned)(v.w <= thrf);
                mask = mask + mask + (unsigned)(v.z <= thrf);
                mask = mask + mask + (unsigned)(v.y <= thrf);
                mask = mask + mask + (unsigned)(v.x <= thrf);
            }
            // phase 2: process only candidates (wave cost = max popcount)
            while (__any((int)(mask != 0u))) {
                if (mask) {
                    int j = __ffs(mask) - 1;
                    mask &= mask - 1u;
                    float d = gq[j];
                    unsigned pk = (flip_f(d) & 0xFFFFF000u)
                                | (unsigned)(kbase + h * 64 + sub * 32 + j);
                    if (pk < lst[KNN - 1]) {
                        lst[KNN - 1] = pk;
#pragma unroll
                        for (int s = KNN - 1; s > 0; --s) {
                            if (lst[s] < lst[s - 1]) {
                                unsigned tmp = lst[s]; lst[s] = lst[s - 1]; lst[s - 1] = tmp;
                            }
                        }
                    }
                }
            }
            thrx[t] = thr_of(lst[KNN - 1]);   // publish fresh own 16th
            __syncthreads();   // scan readers done: h1 dump / next-kt staging safe
        }
    }

    // merge the two per-query sublists (threads t and t+128)
    unsigned* mls = (unsigned*)smem;   // [256][17] u32 = 17408 B (buf0 dead)
#pragma unroll
    for (int j = 0; j < KNN; ++j) mls[t * 17 + j] = lst[j];
    __syncthreads();
    if (t < 128) {
        const unsigned* da = mls + t * 17;
        const unsigned* db = mls + (t + 128) * 17;
        unsigned* outp = Dp + ((size_t)((b * NPTS + q0 + t) * 2 + ks)) * KNN;
        int ia = 0, ib2 = 0;
        for (int k = 0; k < KNN; ++k) {
            bool ta = (ib2 >= KNN) || (ia < KNN && da[ia] < db[ib2]);
            outp[k] = ta ? da[ia++] : db[ib2++];
        }
    }
}

// ---------------- transpose: X2 [b][c][n] -> Xt [b][n][256] ------------------
// Fallback only (ws too small for a dedicated Xt region).
__global__ __launch_bounds__(256) void transpose_kernel(
    const float* __restrict__ X2, float* __restrict__ Xt) {
    __shared__ float T[64][65];
    int b = blockIdx.x;
    int n0 = blockIdx.y * 64;
    int t = threadIdx.x;
    int wave = t >> 6, lane = t & 63;
    for (int cc = 0; cc < 4; ++cc) {
        for (int r = 0; r < 16; ++r) {
            int cl = r * 4 + (t >> 6);
            T[cl][t & 63] = X2[((size_t)b * 256 + cc * 64 + cl) * NPTS + n0 + (t & 63)];
        }
        __syncthreads();
#pragma unroll
        for (int r = 0; r < 16; ++r) {
            int n_l = wave * 16 + r;
            Xt[((size_t)b * NPTS + n0 + n_l) * 256 + cc * 64 + lane] = T[lane][n_l];
        }
        __syncthreads();
    }
}

// ---------------- fused merge2 + gather + max over K + partial pool ----------
__global__ __launch_bounds__(256) void gather_pool_kernel(
    const float* __restrict__ Xt, const unsigned* __restrict__ Dp,
    float* __restrict__ Pp) {
    __shared__ int idxs[16][KNN];
    int b = blockIdx.x, blk = blockIdx.y;
    int t = threadIdx.x;
    if (t < 16) {
        int qg = b * NPTS + blk * 16 + t;
        const unsigned* L0 = Dp + (size_t)qg * 2 * KNN;
        const unsigned* L1 = L0 + KNN;
        int p0 = 0, p1 = 0;
#pragma unroll 1
        for (int k = 0; k < KNN; ++k) {
            bool ta = (p1 >= KNN) || (p0 < KNN && L0[p0] < L1[p1]);
            idxs[t][k] = (int)((ta ? L0[p0++] : L1[p1++]) & 0xFFFu);
        }
    }
    __syncthreads();
    int wv = t >> 6, lane = t & 63;
    const float* xb = Xt + (size_t)b * NPTS * 256;
    f32x4 sum = (f32x4){0.f, 0.f, 0.f, 0.f};
#pragma unroll 1
    for (int i = 0; i < 4; ++i) {
        const int* idp = idxs[wv * 4 + i];
        f32x4 m = *(const f32x4*)(xb + (size_t)idp[0] * 256 + lane * 4);
#pragma unroll
        for (int k = 1; k < KNN; ++k) {
            f32x4 v = *(const f32x4*)(xb + (size_t)idp[k] * 256 + lane * 4);
            m.x = fmaxf(m.x, v.x); m.y = fmaxf(m.y, v.y);
            m.z = fmaxf(m.z, v.z); m.w = fmaxf(m.w, v.w);
        }
        sum.x += m.x; sum.y += m.y; sum.z += m.z; sum.w += m.w;
    }
    __shared__ float S[4][256];
    *(f32x4*)&S[wv][lane * 4] = sum;
    __syncthreads();
    Pp[((size_t)b * 256 + blk) * 256 + t] = S[0][t] + S[1][t] + S[2][t] + S[3][t];
}

// ---------------- fused final pool + MLP (grid = 8 blocks, one per batch) ----
__global__ __launch_bounds__(256) void pool_mlp_kernel(
    const float* __restrict__ Pp,
    const float* __restrict__ gw0, const float* __restrict__ gb0,
    const float* __restrict__ gw1, const float* __restrict__ gb1,
    const float* __restrict__ gw2, const float* __restrict__ gb2,
    float* __restrict__ out) {
    __shared__ float P[256];
    __shared__ float h1[128];
    __shared__ float h2[64];
    int b = blockIdx.x, t = threadIdx.x;
    double s = 0.0;
#pragma unroll 4
    for (int j = 0; j < 256; ++j) s += (double)Pp[((size_t)b * 256 + j) * 256 + t];
    P[t] = (float)(s / (double)NPTS);
    __syncthreads();
    if (t < 128) {
        const float* w = gw0 + t * 256;
        double acc = 0.0;
        for (int c = 0; c < 256; ++c) acc += (double)P[c] * (double)w[c];
        float v = gb0[t] + (float)acc;
        h1[t] = v > 0.f ? v : 0.f;
    }
    __syncthreads();
    if (t < 64) {
        const float* w = gw1 + t * 128;
        double acc = 0.0;
        for (int c = 0; c < 128; ++c) acc += (double)h1[c] * (double)w[c];
        float v = gb1[t] + (float)acc;
        h2[t] = v > 0.f ? v : 0.f;
    }
    __syncthreads();
    if (t == 0) {
        double acc = 0.0;
        for (int c = 0; c < 64; ++c) acc += (double)h2[c] * (double)gw2[c];
        out[b] = gb2[0] + (float)acc;
    }
}

extern "C" void kernel_launch(void* const* d_in, const int* in_sizes, int n_in,
                              void* d_out, int out_size, void* d_ws, size_t ws_size,
                              hipStream_t stream) {
    const float* pc  = (const float*)d_in[0];
    const float* w0  = (const float*)d_in[1];
    const float* b0  = (const float*)d_in[2];
    const float* g0  = (const float*)d_in[3];
    const float* be0 = (const float*)d_in[4];
    const float* w1  = (const float*)d_in[5];
    const float* b1  = (const float*)d_in[6];
    const float* g1  = (const float*)d_in[7];
    const float* be1 = (const float*)d_in[8];
    const float* w2  = (const float*)d_in[9];
    const float* b2  = (const float*)d_in[10];
    const float* g2  = (const float*)d_in[11];
    const float* be2 = (const float*)d_in[12];
    const float* gw0 = (const float*)d_in[13];
    const float* gb0 = (const float*)d_in[14];
    const float* gw1 = (const float*)d_in[15];
    const float* gb1 = (const float*)d_in[16];
    const float* gw2 = (const float*)d_in[17];
    const float* gb2 = (const float*)d_in[18];
    float* out = (float*)d_out;

    // ws layout (floats). Region reuse timeline:
    //   X0 (2,097,152 f): conv0 act -> Dp (knn packed u32 lists, 1,048,576 u32
    //                     = 4 MB; live through gather_pool)
    //   X2 (8,388,608 f): conv2 act (live through convert/transpose)
    //   R  (11,534,336 f): X1 (conv1) -> Fc (4,718,592 f: bf16-hi)
    //                      [fallback only: -> Xt after knn]
    //   tail: SQ, P(pad), Pp, [roomy only: Xt2]
    float* ws = (float*)d_ws;
    float* X0 = ws;
    float* X2 = X0 + 2097152;
    float* R  = X2 + 8388608;
    float* X1 = R;
    unsigned short* Fc = (unsigned short*)R;          // 9,437,184 shorts (hi only)
    unsigned* Dp = (unsigned*)X0;                     // 1,048,576 u32 (2 lists/q)
    float* SQ = R + 11534336;                         // 32,768 f
    float* P  = SQ + 32768;                           // 2,048 f (layout pad)
    float* Pp = P + 2048;                             // 524,288 f
    float* Xt2 = Pp + 524288;                         // 8,388,608 f (roomy only)

    // roomy: dedicated Xt region -> convert emits Xt from its LDS tiles and
    // the standalone transpose launch (+33.6 MB X2 re-read) is skipped.
    bool roomy = ws_size >= (size_t)(22579200ull + 8388608ull) * 4ull;
    float* Xt = roomy ? Xt2 : R;   // fallback: Xt overwrites Fc after knn

    // fused conv+LN: grid (batch, co-groups) -> same-batch blocks co-XCD.
    conv_ln_kernel<3, 2><<<dim3(BATCH, 64 / 2), 256, 0, stream>>>(
        pc, w0, b0, g0, be0, X0, 64);
    conv_ln_kernel<64, 4><<<dim3(BATCH, 128 / 4), 256, 0, stream>>>(
        X0, w1, b1, g1, be1, X1, 128);
    conv_ln_kernel<128, 4><<<dim3(BATCH, 256 / 4), 256, 0, stream>>>(
        X1, w2, b2, g2, be2, X2, 256);

    convert_kernel<<<dim3(NPTS / 64, BATCH), 256, 0, stream>>>(
        X2, Fc, SQ, roomy ? Xt2 : nullptr);                      // overwrites X1 (dead)
    knn_mfma_kernel<<<dim3(BATCH, 32, 2), 256, 0, stream>>>(Fc, SQ, Dp);
    if (!roomy)
        transpose_kernel<<<dim3(BATCH, NPTS / 64), 256, 0, stream>>>(X2, Xt);
    gather_pool_kernel<<<dim3(BATCH, 256), 256, 0, stream>>>(Xt, Dp, Pp);
    pool_mlp_kernel<<<dim3(BATCH), 256, 0, stream>>>(Pp, gw0, gb0, gw1, gb1, gw2, gb2, out);
}